// Round 8
// baseline (217.161 us; speedup 1.0000x reference)
//
#include <hip/hip_runtime.h>
#include <math.h>

#define N_NODES   16000
#define N_EDGES   512000
#define EMBED_DIM 28
#define NODE_DIM  128
#define NUM_BASIS 20

#define EPB   128                   // edges per block
#define NBLK  (N_EDGES / EPB)       // 4000 blocks, exact

// LDS pattern table: 9 patterns, pattern j at dword offset j*PSTRIDE + e*4.
// PSTRIDE = 516 dwords (= 128 f4 + 16B skew) so patterns land on shifted
// banks: p and p+8 alias -> <=2-way conflicts on phase-3 gathers (free).
#define PSTRIDE 516
#define PAT_DWORDS (8 * PSTRIDE + EPB * 4)   // 4640 dwords = 18.56 KB

typedef float f32x4 __attribute__((ext_vector_type(4)));

// ---------------------------------------------------------------------------
// x_scalar[node][d] = dot(embed_table[at_no[node]], W[d]) + b[d]
// ---------------------------------------------------------------------------
__global__ __launch_bounds__(256) void node_kernel(
    const int*   __restrict__ at_no,
    const float* __restrict__ embed,
    const float* __restrict__ W,
    const float* __restrict__ b,
    float*       __restrict__ out)
{
    int idx = blockIdx.x * 256 + threadIdx.x;
    if (idx >= N_NODES * NODE_DIM) return;
    int node = idx >> 7;
    int d    = idx & 127;
    int a    = at_no[node];
    const float* er = embed + a * EMBED_DIM;
    const float* wr = W + d * EMBED_DIM;
    float sum = b[d];
#pragma unroll
    for (int k = 0; k < EMBED_DIM; ++k)
        sum = fmaf(er[k], wr[k], sum);
    out[idx] = sum;
}

// ---------------------------------------------------------------------------
// Fused edge kernel, 128 threads / 128 edges per block.
// Phase 1: edge compute -> fcut direct, rbf -> LDS, 9 f4 patterns -> LDS.
// Phase 2: coalesced rbf writeout.
// Phase 3: 8 x (15-unrolled) iters: ds_read_b128 -> global_store_dwordx4.
// ---------------------------------------------------------------------------
__global__ __launch_bounds__(128) void fused_edge_kernel(
    const float* __restrict__ pos,
    const int*   __restrict__ eidx,
    float*       __restrict__ rbf,
    float*       __restrict__ fcut,
    float*       __restrict__ rsh)
{
    __shared__ float sh_pat[PAT_DWORDS];    // 18.56 KB
    __shared__ float sh_rbf[EPB * 20];      // 10 KB, flat edge-major

    const int t  = threadIdx.x;
    const int e0 = blockIdx.x * EPB;
    const int e  = e0 + t;

    // ---- Phase 1: edge compute ----
    {
        int s  = eidx[e];
        int dn = eidx[N_EDGES + e];

        // reference permutes pos columns by [1,2,0]
        float ax = pos[s*3+1],  ay = pos[s*3+2],  az = pos[s*3+0];
        float bx = pos[dn*3+1], by = pos[dn*3+2], bz = pos[dn*3+0];
        float vx = ax - bx, vy = ay - by, vz = az - bz;
        float dist = sqrtf(vx*vx + vy*vy + vz*vz);
        float inv  = 1.0f / dist;
        float ux = vx*inv, uy = vy*inv, uz = vz*inv;

        const float S3  = 1.7320508075688772f;
        const float S5  = 2.2360679774997896f;
        const float S15 = 3.8729833462074170f;
        float s0 = S3 * ux, s1 = S3 * uy, s2 = S3 * uz;
        float t0 = S15 * ux * uz;
        float t1 = S15 * ux * uy;
        float t2 = S5  * (uy*uy - 0.5f*(ux*ux + uz*uz));
        float t3 = S15 * uy * uz;
        float t4 = 0.5f * S15 * (uz*uz - ux*ux);

        f32x4* pb = (f32x4*)(sh_pat) + t;        // pattern j at + j*PSTRIDE/4
#define PW(j, a_, b_, c_, d_) { f32x4 v_; v_.x=a_; v_.y=b_; v_.z=c_; v_.w=d_; \
                                pb[(j) * (PSTRIDE/4)] = v_; }
        PW(0, 1.0f, 1.0f, 1.0f, 1.0f)
        PW(1, s0, s1, s2, s0)
        PW(2, s1, s2, s0, s1)
        PW(3, s2, s0, s1, s2)
        PW(4, t0, t1, t2, t3)
        PW(5, t1, t2, t3, t4)
        PW(6, t2, t3, t4, t0)
        PW(7, t3, t4, t0, t1)
        PW(8, t4, t0, t1, t2)
#undef PW

        // cutoff poly p=5: 1 - 21u^5 + 35u^6 - 15u^7
        float u  = dist * 0.2f;
        float u2 = u*u, u5 = u2*u2*u;
        float f  = 1.0f + u5*(-21.0f + u*(35.0f - 15.0f*u));
        fcut[e] = (u < 1.0f) ? f : 0.0f;

        // rbf[n] = sqrt(2/5) * sin(n*pi*dist/5)/dist via Chebyshev recurrence
        float th = 0.62831853071795864769f * dist;   // pi/5 * dist
        float sn = __sinf(th), cs = __cosf(th);
        float twoc = 2.0f * cs;
        float kk = 0.6324555320336759f * inv;
        float sp = 0.0f, sc = sn;
        f32x4* rb = (f32x4*)(sh_rbf + t * 20);
#pragma unroll
        for (int q = 0; q < 5; ++q) {
            f32x4 v_;
            v_.x = kk * sc; { float nx = twoc*sc - sp; sp = sc; sc = nx; }
            v_.y = kk * sc; { float nx = twoc*sc - sp; sp = sc; sc = nx; }
            v_.z = kk * sc; { float nx = twoc*sc - sp; sp = sc; sc = nx; }
            v_.w = kk * sc; { float nx = twoc*sc - sp; sp = sc; sc = nx; }
            rb[q] = v_;
        }
    }
    __syncthreads();

    // ---- Phase 2: coalesced rbf writeout (5 x 128 float4) ----
    {
        const f32x4* ls = (const f32x4*)sh_rbf;
        f32x4* go = (f32x4*)(rbf + (size_t)e0 * NUM_BASIS);
#pragma unroll
        for (int q = 0; q < 5; ++q)
            go[q * EPB + t] = ls[q * EPB + t];
    }

    // ---- Phase 3: rsh stream ----
    // Global f4 slot (relative to block) g = (i*15 + k)*128 + t, i<8, k<15.
    // le = g/120, c = g%120. Selector sequence has period 15 in k
    // (15*128 = 16*120), le advances exactly +16 per outer iter.
    {
        // Precompute 15 LDS dword-offsets: off_k = p(c_k)*PSTRIDE + d_k*4
        int offs[15];
#pragma unroll
        for (int k = 0; k < 15; ++k) {
            int u  = k * 128 + t;        // < 1920
            int d  = u / 120;
            int c  = u - d * 120;
            int p;
            if (c < 32)      p = 0;
            else if (c < 80) p = 1 + (c - 32) % 3;
            else             p = 4 + (4 * (c - 80)) % 5;
            offs[k] = p * PSTRIDE + d * 4;
        }

        float* outb = rsh + (size_t)e0 * 480 + (size_t)t * 4;
        int base = 0;                    // += 64 dwords (16 edges) per outer

#pragma unroll 1
        for (int i = 0; i < 8; ++i) {
#pragma unroll
            for (int k = 0; k < 15; ++k) {
                f32x4 v = *(const f32x4*)(sh_pat + base + offs[k]);
                *(f32x4*)(outb + (size_t)k * 512) = v;   // 512 floats = 128 f4
            }
            base += 64;
            outb += 15 * 512;
        }
    }
}

extern "C" void kernel_launch(void* const* d_in, const int* in_sizes, int n_in,
                              void* d_out, int out_size, void* d_ws, size_t ws_size,
                              hipStream_t stream) {
    const int*   at_no = (const int*)  d_in[0];
    const float* pos   = (const float*)d_in[1];
    const int*   eidx  = (const int*)  d_in[2];
    const float* embed = (const float*)d_in[3];
    const float* W     = (const float*)d_in[4];
    const float* b     = (const float*)d_in[5];

    float* out      = (float*)d_out;
    float* x_scalar = out;                                   // 16000*128
    float* rbf      = x_scalar + (size_t)N_NODES * NODE_DIM; // 512000*20
    float* fcut     = rbf + (size_t)N_EDGES * NUM_BASIS;     // 512000
    float* rsh      = fcut + N_EDGES;                        // 512000*480

    node_kernel<<<(N_NODES * NODE_DIM + 255) / 256, 256, 0, stream>>>(
        at_no, embed, W, b, x_scalar);

    fused_edge_kernel<<<NBLK, 128, 0, stream>>>(
        pos, eidx, rbf, fcut, rsh);
}